// Round 1
// baseline (373.265 us; speedup 1.0000x reference)
//
#include <hip/hip_runtime.h>

// PoolingRetriever collapses: softmax over a size-1 axis == 1.0, so
//   out = (x @ Wv.T + bv) @ Wo.T + bo
// x: (65536, 768) f32.  Wv: (64,768).  Wo: (768,64).  out: (65536,768) f32.
// Memory-bound: ~402 MB HBM traffic floor. Compute done in bf16 MFMA.

#define DIM 768
#define NB  64     // H*HD
#define MT  64     // rows per block
#define NCH 128    // phase-2 n-chunk

typedef __attribute__((ext_vector_type(8))) short short8;
typedef __attribute__((ext_vector_type(4))) float f32x4;
typedef __attribute__((ext_vector_type(4))) unsigned short ushort4_t;

__device__ __forceinline__ unsigned short f2bf(float f) {
    union { float f; unsigned int u; } v; v.f = f;
    return (unsigned short)((v.u + 0x7fffu + ((v.u >> 16) & 1u)) >> 16);
}

__global__ __launch_bounds__(256, 4)
void pooling_retriever_fused(const float* __restrict__ x,
                             const float* __restrict__ Wv, const float* __restrict__ bv,
                             const float* __restrict__ Wo, const float* __restrict__ bo,
                             float* __restrict__ out)
{
    // LDS: row strides padded for bank spread; all strides keep 16B alignment
    __shared__ unsigned short sA[64 * 40];    // x chunk   (64 rows x 32 k), stride 40
    __shared__ unsigned short sW[64 * 40];    // Wv chunk  (64 n    x 32 k)
    __shared__ unsigned short sV[64 * 72];    // V tile    (64 rows x 64 j), stride 72
    __shared__ unsigned short sWo[128 * 72];  // Wo chunk  (128 n   x 64 j)

    const int tid  = threadIdx.x;
    const int wave = tid >> 6;
    const int lane = tid & 63;
    const int lq   = lane >> 4;   // quad 0..3
    const int lm   = lane & 15;
    const int row0 = blockIdx.x * MT;

    // ---------------- Phase 1: V = x @ Wv.T  (per wave: 16 rows x 64 n) ----
    f32x4 accV[4];
    #pragma unroll
    for (int t = 0; t < 4; ++t) accV[t] = (f32x4){0.f, 0.f, 0.f, 0.f};

    for (int kc = 0; kc < DIM / 32; ++kc) {
        const int k0 = kc * 32;
        __syncthreads();  // protect sA/sW from previous iteration's reads
        #pragma unroll
        for (int i = 0; i < 2; ++i) {
            const int f  = tid + 256 * i;   // 0..511 float4s
            const int r  = f >> 3;          // 0..63 row
            const int c4 = f & 7;           // float4 within 32 floats
            const float4 va = *(const float4*)(x  + (size_t)(row0 + r) * DIM + k0 + c4 * 4);
            const float4 vw = *(const float4*)(Wv + (size_t)r * DIM + k0 + c4 * 4);
            const int sidx = r * 40 + c4 * 4;
            ushort4_t pa, pw;
            pa[0] = f2bf(va.x); pa[1] = f2bf(va.y); pa[2] = f2bf(va.z); pa[3] = f2bf(va.w);
            pw[0] = f2bf(vw.x); pw[1] = f2bf(vw.y); pw[2] = f2bf(vw.z); pw[3] = f2bf(vw.w);
            *(ushort4_t*)&sA[sidx] = pa;
            *(ushort4_t*)&sW[sidx] = pw;
        }
        __syncthreads();
        const short8 a = *(const short8*)&sA[(wave * 16 + lm) * 40 + lq * 8];
        #pragma unroll
        for (int t = 0; t < 4; ++t) {
            const short8 b = *(const short8*)&sW[(t * 16 + lm) * 40 + lq * 8];
            accV[t] = __builtin_amdgcn_mfma_f32_16x16x32_bf16(a, b, accV[t], 0, 0, 0);
        }
    }

    // ------------- Phase 1.5: V + bv -> sV (bf16), C-layout -> A-layout ----
    #pragma unroll
    for (int t = 0; t < 4; ++t) {
        const int n = t * 16 + lm;           // C col = lane&15
        const float bvn = bv[n];
        #pragma unroll
        for (int r = 0; r < 4; ++r) {
            const int m = lq * 4 + r;        // C row = quad*4 + reg
            sV[(wave * 16 + m) * 72 + n] = f2bf(accV[t][r] + bvn);
        }
    }
    __syncthreads();
    // Preload phase-2 A fragments (each wave reads only its own 16 rows)
    const short8 aV0 = *(const short8*)&sV[(wave * 16 + lm) * 72 + 0  + lq * 8];
    const short8 aV1 = *(const short8*)&sV[(wave * 16 + lm) * 72 + 32 + lq * 8];

    // ---------------- Phase 2: out = V @ Wo.T + bo -------------------------
    for (int nc = 0; nc < DIM / NCH; ++nc) {
        const int n0 = nc * NCH;
        __syncthreads();  // protect sWo from previous chunk's reads
        #pragma unroll
        for (int i = 0; i < 8; ++i) {
            const int f  = tid + 256 * i;   // 0..2047 float4s
            const int r  = f >> 4;          // 0..127 Wo row
            const int c4 = f & 15;          // float4 within 64 floats
            const float4 vw = *(const float4*)(Wo + (size_t)(n0 + r) * NB + c4 * 4);
            ushort4_t pw;
            pw[0] = f2bf(vw.x); pw[1] = f2bf(vw.y); pw[2] = f2bf(vw.z); pw[3] = f2bf(vw.w);
            *(ushort4_t*)&sWo[r * 72 + c4 * 4] = pw;
        }
        __syncthreads();
        f32x4 acc[8];
        #pragma unroll
        for (int t = 0; t < 8; ++t) acc[t] = (f32x4){0.f, 0.f, 0.f, 0.f};
        #pragma unroll
        for (int t = 0; t < 8; ++t) {
            const short8 b0 = *(const short8*)&sWo[(t * 16 + lm) * 72 + 0  + lq * 8];
            acc[t] = __builtin_amdgcn_mfma_f32_16x16x32_bf16(aV0, b0, acc[t], 0, 0, 0);
            const short8 b1 = *(const short8*)&sWo[(t * 16 + lm) * 72 + 32 + lq * 8];
            acc[t] = __builtin_amdgcn_mfma_f32_16x16x32_bf16(aV1, b1, acc[t], 0, 0, 0);
        }
        // epilogue: out[row][col] = acc + bo[col]
        #pragma unroll
        for (int t = 0; t < 8; ++t) {
            const int col = n0 + t * 16 + lm;
            const float boc = bo[col];
            #pragma unroll
            for (int r = 0; r < 4; ++r) {
                const int m = row0 + wave * 16 + lq * 4 + r;
                out[(size_t)m * DIM + col] = acc[t][r] + boc;
            }
        }
    }
}

extern "C" void kernel_launch(void* const* d_in, const int* in_sizes, int n_in,
                              void* d_out, int out_size, void* d_ws, size_t ws_size,
                              hipStream_t stream) {
    const float* x  = (const float*)d_in[0];
    // d_in[1..5] = q_state, Wq, bq, Wk, bk — mathematically unused (softmax over
    // a size-1 axis is identically 1, so xi stays all-ones and out = v path only)
    const float* Wv = (const float*)d_in[6];
    const float* bv = (const float*)d_in[7];
    const float* Wo = (const float*)d_in[8];
    const float* bo = (const float*)d_in[9];
    float* out = (float*)d_out;

    const int Bn = in_sizes[0] / DIM;  // 65536
    pooling_retriever_fused<<<dim3(Bn / MT), dim3(256), 0, stream>>>(x, Wv, bv, Wo, bo, out);
}

// Round 2
// 372.362 us; speedup vs baseline: 1.0024x; 1.0024x over previous
//
#include <hip/hip_runtime.h>

// PoolingRetriever collapses: softmax over a size-1 axis == 1.0, so
//   out = (x @ Wv.T + bv) @ Wo.T + bo
// x: (65536,768) f32. Wv: (64,768). Wo: (768,64). out: (65536,768) f32.
//
// Barrier-free design: weights are pre-packed (pack_weights kernel) into
// MFMA B-fragment order as bf16 in d_ws, so every wave loads its fragments
// directly from global (L2-resident, 16B/lane coalesced). x A-fragments are
// loaded straight from global (8 consecutive f32 per lane -> cvt bf16).
// Only one __syncthreads in the whole kernel (V C->A layout LDS transpose).

#define DIM 768
#define NB  64
#define KC  (DIM / 32)          // 24 k-chunks of 32
#define RPW 32                  // rows per wave
#define WPB 2                   // waves per block (128 threads)
#define RPB (RPW * WPB)         // 64 rows per block
#define WV_ELEMS (NB * DIM)     // 49152 per weight matrix

typedef __attribute__((ext_vector_type(8))) short short8;
typedef __attribute__((ext_vector_type(4))) float f32x4;

__device__ __forceinline__ unsigned short f2bf(float f) {
    union { float f; unsigned int u; } v; v.f = f;
    return (unsigned short)((v.u + 0x7fffu + ((v.u >> 16) & 1u)) >> 16);
}

__device__ __forceinline__ short8 pack_bf8(float4 lo, float4 hi) {
    short8 r;
    r[0] = (short)f2bf(lo.x); r[1] = (short)f2bf(lo.y);
    r[2] = (short)f2bf(lo.z); r[3] = (short)f2bf(lo.w);
    r[4] = (short)f2bf(hi.x); r[5] = (short)f2bf(hi.y);
    r[6] = (short)f2bf(hi.z); r[7] = (short)f2bf(hi.w);
    return r;
}

// Pack Wv and Wo (f32, row-major) into bf16 MFMA B-fragment order.
// pWv frag (kc,t): element idx ((kc*4+t)*64 + lane)*8 + j holds
//   Wv[n = t*16 + (lane&15)][k = kc*32 + (lane>>4)*8 + j]
// pWo frag (tile,h): element idx ((tile*2+h)*64 + lane)*8 + j holds
//   Wo[n = tile*16 + (lane&15)][jd = h*32 + (lane>>4)*8 + j]
__global__ void pack_weights(const float* __restrict__ Wv, const float* __restrict__ Wo,
                             unsigned short* __restrict__ pWv, unsigned short* __restrict__ pWo) {
    int e = blockIdx.x * 256 + threadIdx.x;      // 0 .. 2*49152-1
    int which = (e >= WV_ELEMS) ? 1 : 0;
    int idx = which ? e - WV_ELEMS : e;
    int frag = idx >> 9;                          // per-frag: 64 lanes * 8 elems
    int lane = (idx >> 3) & 63;
    int j = idx & 7;
    int lm = lane & 15, lq = lane >> 4;
    float v;
    if (!which) {
        int kc = frag >> 2, t = frag & 3;
        v = Wv[(t * 16 + lm) * DIM + kc * 32 + lq * 8 + j];
    } else {
        int tile = frag >> 1, h = frag & 1;
        v = Wo[(tile * 16 + lm) * NB + h * 32 + lq * 8 + j];
    }
    (which ? pWo : pWv)[idx] = f2bf(v);
}

__global__ __launch_bounds__(128, 4)
void pr_main(const float* __restrict__ x,
             const unsigned short* __restrict__ pWv, const float* __restrict__ bv,
             const unsigned short* __restrict__ pWo, const float* __restrict__ bo,
             float* __restrict__ out)
{
    __shared__ unsigned short sV[WPB][RPW][72];   // 2*32*72*2 = 9216 B

    const int tid  = threadIdx.x;
    const int wave = tid >> 6;
    const int lane = tid & 63;
    const int lq   = lane >> 4;
    const int lm   = lane & 15;
    const long row0 = (long)blockIdx.x * RPB + wave * RPW;

    // ---------------- Phase 1: V = x @ Wv.T (per wave: 32 rows x 64 n) ----
    f32x4 accV[2][4];
    #pragma unroll
    for (int s = 0; s < 2; ++s)
        #pragma unroll
        for (int t = 0; t < 4; ++t) accV[s][t] = (f32x4){0.f, 0.f, 0.f, 0.f};

    const float* xb0 = x + (row0 + lm) * DIM + lq * 8;
    const float* xb1 = xb0 + 16 * DIM;
    const short8* wv = (const short8*)pWv + lane;   // + frag*64

    #pragma unroll 2
    for (int kc = 0; kc < KC; ++kc) {
        const float4 a0l = *(const float4*)(xb0 + kc * 32);
        const float4 a0h = *(const float4*)(xb0 + kc * 32 + 4);
        const float4 a1l = *(const float4*)(xb1 + kc * 32);
        const float4 a1h = *(const float4*)(xb1 + kc * 32 + 4);
        const short8 a0 = pack_bf8(a0l, a0h);
        const short8 a1 = pack_bf8(a1l, a1h);
        #pragma unroll
        for (int t = 0; t < 4; ++t) {
            const short8 b = wv[(kc * 4 + t) * 64];
            accV[0][t] = __builtin_amdgcn_mfma_f32_16x16x32_bf16(a0, b, accV[0][t], 0, 0, 0);
            accV[1][t] = __builtin_amdgcn_mfma_f32_16x16x32_bf16(a1, b, accV[1][t], 0, 0, 0);
        }
    }

    // ------- Phase 1.5: V + bv -> LDS (bf16), C-layout -> A-layout --------
    #pragma unroll
    for (int t = 0; t < 4; ++t) {
        const float bvn = bv[t * 16 + lm];
        #pragma unroll
        for (int s = 0; s < 2; ++s) {
            #pragma unroll
            for (int r = 0; r < 4; ++r) {
                sV[wave][s * 16 + lq * 4 + r][t * 16 + lm] = f2bf(accV[s][t][r] + bvn);
            }
        }
    }
    __syncthreads();
    short8 aV[2][2];
    #pragma unroll
    for (int s = 0; s < 2; ++s) {
        aV[s][0] = *(const short8*)&sV[wave][s * 16 + lm][lq * 8];
        aV[s][1] = *(const short8*)&sV[wave][s * 16 + lm][32 + lq * 8];
    }

    // ---------------- Phase 2: out = V @ Wo.T + bo ------------------------
    const short8* wo = (const short8*)pWo + lane;   // + frag*64
    for (int cc = 0; cc < 12; ++cc) {
        f32x4 acc[2][4];
        #pragma unroll
        for (int s = 0; s < 2; ++s)
            #pragma unroll
            for (int t = 0; t < 4; ++t) acc[s][t] = (f32x4){0.f, 0.f, 0.f, 0.f};

        #pragma unroll
        for (int t = 0; t < 4; ++t) {
            const int tile = cc * 4 + t;
            const short8 b0 = wo[(tile * 2 + 0) * 64];
            const short8 b1 = wo[(tile * 2 + 1) * 64];
            #pragma unroll
            for (int s = 0; s < 2; ++s) {
                acc[s][t] = __builtin_amdgcn_mfma_f32_16x16x32_bf16(aV[s][0], b0, acc[s][t], 0, 0, 0);
                acc[s][t] = __builtin_amdgcn_mfma_f32_16x16x32_bf16(aV[s][1], b1, acc[s][t], 0, 0, 0);
            }
        }

        #pragma unroll
        for (int t = 0; t < 4; ++t) {
            const int col = cc * 64 + t * 16 + lm;
            const float boc = bo[col];
            #pragma unroll
            for (int s = 0; s < 2; ++s) {
                #pragma unroll
                for (int r = 0; r < 4; ++r) {
                    out[(row0 + s * 16 + lq * 4 + r) * DIM + col] = acc[s][t][r] + boc;
                }
            }
        }
    }
}

extern "C" void kernel_launch(void* const* d_in, const int* in_sizes, int n_in,
                              void* d_out, int out_size, void* d_ws, size_t ws_size,
                              hipStream_t stream) {
    const float* x  = (const float*)d_in[0];
    // d_in[1..5] = q_state, Wq, bq, Wk, bk — mathematically dead: softmax over
    // the size-1 sequence axis is identically 1, so out depends only on v path.
    const float* Wv = (const float*)d_in[6];
    const float* bv = (const float*)d_in[7];
    const float* Wo = (const float*)d_in[8];
    const float* bo = (const float*)d_in[9];
    float* out = (float*)d_out;

    unsigned short* pWv = (unsigned short*)d_ws;          // 96 KB
    unsigned short* pWo = pWv + WV_ELEMS;                 // 96 KB

    pack_weights<<<dim3(2 * WV_ELEMS / 256), dim3(256), 0, stream>>>(Wv, Wo, pWv, pWo);

    const int Bn = in_sizes[0] / DIM;                     // 65536
    pr_main<<<dim3(Bn / RPB), dim3(128), 0, stream>>>(x, pWv, bv, pWo, bo, out);
}